// Round 1
// baseline (1555.347 us; speedup 1.0000x reference)
//
#include <hip/hip_runtime.h>

#define EPSV 1e-4f

constexpr int Bc = 4, Mc = 32, Hc = 152, Wc = 272;
constexpr int HWc = Hc * Wc;          // 41344
constexpr int WTc = 593;              // (16+2)*16 + 16 + 16*16 + 16 + 16 + 1
constexpr int SPLIT = 8;              // spatial chunks per (b,m); 41344/8 = 5168 exact
constexpr int NBLK = Bc * Mc * SPLIT; // 1024 blocks
constexpr int PX = 4;                 // pixels per thread per iteration

__global__ __launch_bounds__(256) void sch_neg_kernel(
    const float* __restrict__ sch_feat,
    const float* __restrict__ conv_weight,
    const int* __restrict__ pre_ind,
    const float* __restrict__ target,
    const int* __restrict__ ind,
    const float* __restrict__ mask,
    float* __restrict__ ws)
{
  __shared__ float s_w1[16][20];   // padded rows (18 used) -> 16B-aligned rows
  __shared__ float s_b1[16];
  __shared__ float s_w2[16][16];
  __shared__ float s_b2[16];
  __shared__ float s_w3[16];
  __shared__ float s_b3;
  __shared__ float red[256];

  const int blk = blockIdx.x;
  const int bm = blk / SPLIT;
  const int chunk = blk - bm * SPLIT;
  const int b = bm / Mc;

  const int p = pre_ind[bm];

  // ---- stage the 593 gathered weights into LDS, split into layer tensors ----
  for (int j = threadIdx.x; j < WTc; j += 256) {
    float v = conv_weight[(size_t)(b * WTc + j) * HWc + p];
    if (j < 288)      s_w1[j / 18][j % 18] = v;
    else if (j < 304) s_b1[j - 288] = v;
    else if (j < 560) { int k = j - 304; s_w2[k >> 4][k & 15] = v; }
    else if (j < 576) s_b2[j - 560] = v;
    else if (j < 592) s_w3[j - 576] = v;
    else              s_b3 = v;
  }
  __syncthreads();

  const float x0 = (float)(p % Wc);
  const float y0 = (float)p / (float)Wc;   // NOTE: float division of flat index (per reference)
  const float* __restrict__ sf = sch_feat + (size_t)b * 16 * HWc;
  const float* __restrict__ tg = target + (size_t)bm * HWc;

  // ---- positive-sample term: one thread per (b,m), on the chunk-0 block ----
  if (chunk == 0 && threadIdx.x == 0) {
    const int pi = ind[bm];
    float f[18];
    #pragma unroll
    for (int c = 0; c < 16; c++) f[c] = sf[c * HWc + pi];
    int hh = pi / Wc, wwp = pi - hh * Wc;
    f[16] = ((float)wwp - x0) * (1.0f / 128.0f);
    f[17] = ((float)hh - y0) * (1.0f / 128.0f);
    float h1[16];
    #pragma unroll
    for (int o = 0; o < 16; o++) {
      float a = s_b1[o];
      #pragma unroll
      for (int c = 0; c < 18; c++) a = fmaf(s_w1[o][c], f[c], a);
      h1[o] = fmaxf(a, 0.0f);
    }
    float h2[16];
    #pragma unroll
    for (int o = 0; o < 16; o++) {
      float a = s_b2[o];
      #pragma unroll
      for (int c = 0; c < 16; c++) a = fmaf(s_w2[o][c], h1[c], a);
      h2[o] = fmaxf(a, 0.0f);
    }
    float z = s_b3;
    #pragma unroll
    for (int c = 0; c < 16; c++) z = fmaf(s_w3[c], h2[c], z);
    float hm = __fdividef(1.0f, 1.0f + __expf(-z));
    hm = fminf(fmaxf(hm, EPSV), 1.0f - EPSV);
    float om = 1.0f - hm;
    ws[NBLK + bm] = __logf(hm) * om * om * mask[bm];
  }

  // ---- negative loss over this block's pixel chunk, PX pixels/thread ----
  const int per = HWc / SPLIT;   // 5168
  const int start = chunk * per;
  const int end = start + per;

  float acc = 0.0f;
  for (int base = start + (int)threadIdx.x; base < end; base += 256 * PX) {
    int idxv[PX]; float wv[PX];
    #pragma unroll
    for (int i = 0; i < PX; i++) {
      int idx = base + i * 256;
      bool v = idx < end;
      idxv[i] = v ? idx : end - 1;   // clamp keeps loads in-bounds
      wv[i] = v ? 1.0f : 0.0f;
    }
    float f[PX][18];
    #pragma unroll
    for (int c = 0; c < 16; c++) {
      #pragma unroll
      for (int i = 0; i < PX; i++) f[i][c] = sf[c * HWc + idxv[i]];
    }
    #pragma unroll
    for (int i = 0; i < PX; i++) {
      int idx = idxv[i];
      int hh = idx / Wc, wwp = idx - hh * Wc;
      f[i][16] = ((float)wwp - x0) * (1.0f / 128.0f);
      f[i][17] = ((float)hh - y0) * (1.0f / 128.0f);
    }
    float h1[16][PX];
    #pragma unroll
    for (int o = 0; o < 16; o++) {
      float wr[18];
      #pragma unroll
      for (int c = 0; c < 18; c++) wr[c] = s_w1[o][c];
      float bb = s_b1[o];
      #pragma unroll
      for (int i = 0; i < PX; i++) {
        float a = bb;
        #pragma unroll
        for (int c = 0; c < 18; c++) a = fmaf(wr[c], f[i][c], a);
        h1[o][i] = fmaxf(a, 0.0f);
      }
    }
    float h2[16][PX];
    #pragma unroll
    for (int o = 0; o < 16; o++) {
      float wr[16];
      #pragma unroll
      for (int c = 0; c < 16; c++) wr[c] = s_w2[o][c];
      float bb = s_b2[o];
      #pragma unroll
      for (int i = 0; i < PX; i++) {
        float a = bb;
        #pragma unroll
        for (int c = 0; c < 16; c++) a = fmaf(wr[c], h1[c][i], a);
        h2[o][i] = fmaxf(a, 0.0f);
      }
    }
    float w3r[16];
    #pragma unroll
    for (int c = 0; c < 16; c++) w3r[c] = s_w3[c];
    const float b3r = s_b3;
    #pragma unroll
    for (int i = 0; i < PX; i++) {
      float z = b3r;
      #pragma unroll
      for (int c = 0; c < 16; c++) z = fmaf(w3r[c], h2[c][i], z);
      float hm = __fdividef(1.0f, 1.0f + __expf(-z));
      hm = fminf(fmaxf(hm, EPSV), 1.0f - EPSV);
      float t = tg[idxv[i]];
      float u = 1.0f - t;
      float u2 = u * u;
      acc += wv[i] * (__logf(1.0f - hm) * hm * hm * (u2 * u2));
    }
  }

  // ---- deterministic block reduction ----
  red[threadIdx.x] = acc;
  __syncthreads();
  for (int s = 128; s > 0; s >>= 1) {
    if ((int)threadIdx.x < s) red[threadIdx.x] += red[threadIdx.x + s];
    __syncthreads();
  }
  if (threadIdx.x == 0) ws[blk] = red[0];
}

__global__ __launch_bounds__(256) void sch_final_kernel(
    const float* __restrict__ ws, const float* __restrict__ mask,
    float* __restrict__ out)
{
  __shared__ float red[256];
  const int t = threadIdx.x;

  float s = 0.0f;
  for (int i = t; i < NBLK; i += 256) s += ws[i];
  red[t] = s; __syncthreads();
  for (int k = 128; k > 0; k >>= 1) { if (t < k) red[t] += red[t + k]; __syncthreads(); }
  const float neg = red[0];
  __syncthreads();

  float pv = (t < Bc * Mc) ? ws[NBLK + t] : 0.0f;
  red[t] = pv; __syncthreads();
  for (int k = 128; k > 0; k >>= 1) { if (t < k) red[t] += red[t + k]; __syncthreads(); }
  const float pos = red[0];
  __syncthreads();

  float mv = (t < Bc * Mc) ? mask[t] : 0.0f;
  red[t] = mv; __syncthreads();
  for (int k = 128; k > 0; k >>= 1) { if (t < k) red[t] += red[t + k]; __syncthreads(); }

  if (t == 0) {
    float np = red[0];
    float loss = (np == 0.0f) ? (-neg) : (-(pos + neg) / fmaxf(np, 1.0f));
    out[0] = loss;
  }
}

extern "C" void kernel_launch(void* const* d_in, const int* in_sizes, int n_in,
                              void* d_out, int out_size, void* d_ws, size_t ws_size,
                              hipStream_t stream)
{
  const float* sch_feat    = (const float*)d_in[0];
  const float* conv_weight = (const float*)d_in[1];
  const float* mask        = (const float*)d_in[2];
  const int*   pre_ind     = (const int*)d_in[3];
  const float* target      = (const float*)d_in[4];
  const int*   ind         = (const int*)d_in[5];
  float* out = (float*)d_out;
  float* ws  = (float*)d_ws;

  sch_neg_kernel<<<dim3(NBLK), dim3(256), 0, stream>>>(
      sch_feat, conv_weight, pre_ind, target, ind, mask, ws);
  sch_final_kernel<<<dim3(1), dim3(256), 0, stream>>>(ws, mask, out);
}

// Round 2
// 256.053 us; speedup vs baseline: 6.0743x; 6.0743x over previous
//
#include <hip/hip_runtime.h>

typedef unsigned int uint;
typedef unsigned short ushort;

constexpr int Bc = 4, Mc = 32, Hc = 152, Wc = 272;
constexpr int HWc = Hc * Wc;            // 41344
constexpr int WTc = 593;                // (16+2)*16 + 16 + 16*16 + 16 + 16 + 1
constexpr int NB = 8;                   // blocks per (b,m)
constexpr int NEG_BLOCKS = Bc * Mc * NB;// 1024
constexpr int ITERS = HWc / 64;         // 646 (exact)
constexpr int WV = NB * 4;              // waves per (b,m) = 32
constexpr int POS_OFF = NEG_BLOCKS;     // ws float index of pos terms
constexpr size_t XOFF_BYTES = 4608;     // start of bf16 x buffer in ws (64B aligned)

using f32x4 = __attribute__((ext_vector_type(4))) float;
using bf16x8 = __attribute__((ext_vector_type(8))) short;

__device__ inline uint pkbf(float lo, float hi) {
  uint r;
  asm("v_cvt_pk_bf16_f32 %0, %1, %2" : "=v"(r) : "v"(lo), "v"(hi));
  return r;
}

// ---- pre-pass: sch_feat fp32 [b][c][hw] -> bf16 pixel-major [b][px][c] ----
__global__ __launch_bounds__(256) void xcvt_kernel(const float* __restrict__ sf,
                                                   ushort* __restrict__ xb) {
  const int b = blockIdx.y;
  const int px = blockIdx.x * 256 + threadIdx.x;
  if (px < HWc) {
    const float* s = sf + (size_t)b * 16 * HWc + px;
    uint o[8];
#pragma unroll
    for (int q = 0; q < 8; q++) o[q] = pkbf(s[(size_t)(2 * q) * HWc], s[(size_t)(2 * q + 1) * HWc]);
    uint4* dst = (uint4*)(xb + ((size_t)b * HWc + px) * 16);
    dst[0] = make_uint4(o[0], o[1], o[2], o[3]);
    dst[1] = make_uint4(o[4], o[5], o[6], o[7]);
  }
  // zero the 128B tail pad (read by over-reaching lanes of the last pixel)
  if (blockIdx.x == 0 && blockIdx.y == 0 && threadIdx.x < 32)
    ((uint*)(xb + (size_t)Bc * HWc * 16))[threadIdx.x] = 0;
}

// ---- main negative-loss kernel: bf16 MFMA MLP over all pixels ----
__global__ __launch_bounds__(256) void sch_neg(const float* __restrict__ cw,
                                               const int* __restrict__ pre_ind,
                                               const float* __restrict__ target,
                                               const ushort* __restrict__ xbf,
                                               float* __restrict__ ws) {
  const int tid = threadIdx.x;
  const int lane = tid & 63;
  const int wid = tid >> 6;
  const int bm = blockIdx.x / NB;
  const int nb = blockIdx.x % NB;
  const int b = bm >> 5;
  const int g = lane >> 4;   // k-group / row-group
  const int o = lane & 15;   // output row (A) / pixel column (B,D)

  const int p = pre_ind[bm];
  const float* wcol = cw + (size_t)b * WTc * HWc + p;
  auto wld = [&](int j) -> float { return wcol[(size_t)j * HWc]; };

  // A fragments (weights), slot e <-> k = 8g+e by OUR convention (A/B consistent)
  float a1f[8], a2f[8];
#pragma unroll
  for (int e = 0; e < 8; e++) {
    int k = 8 * g + e;
    a1f[e] = (k < 16) ? wld(o * 18 + k) : 0.0f;        // w1[o][k]; coords k=16,17 folded into C
    a2f[e] = (k < 16) ? wld(304 + o * 16 + k) : 0.0f;  // w2[o][k]
  }
  union FR { uint u[4]; bf16x8 v; };
  FR A1, A2;
#pragma unroll
  for (int q = 0; q < 4; q++) {
    A1.u[q] = pkbf(a1f[2 * q], a1f[2 * q + 1]);
    A2.u[q] = pkbf(a2f[2 * q], a2f[2 * q + 1]);
  }
  float b1r[4], w16r[4], w17r[4], b2r[4], w3r[4];
#pragma unroll
  for (int r = 0; r < 4; r++) {
    int row = 4 * g + r;                  // D-layout row this lane holds in reg r
    b1r[r] = wld(288 + row);
    w16r[r] = wld(row * 18 + 16);
    w17r[r] = wld(row * 18 + 17);
    b2r[r] = wld(560 + row);
    w3r[r] = wld(576 + row);
  }
  const float b3 = wld(592);
  const float x0 = (float)(p % Wc);
  const float y0 = (float)p / (float)Wc;  // float division of flat index (per reference)

  const ushort* xb = xbf + (size_t)b * HWc * 16;
  const float* tg = target + (size_t)bm * HWc;

  float acc = 0.0f;
  const int gw = nb * 4 + wid;
  for (int it = gw; it < ITERS; it += WV) {
    const int base = it * 64;
    FR B1[4];
    uint4 ld[4];
#pragma unroll
    for (int c = 0; c < 4; c++)
      ld[c] = *(const uint4*)(xb + ((size_t)(base + 16 * c + o)) * 16 + g * 8);
#pragma unroll
    for (int c = 0; c < 4; c++) { B1[c].u[0] = ld[c].x; B1[c].u[1] = ld[c].y; B1[c].u[2] = ld[c].z; B1[c].u[3] = ld[c].w; }
    const float tval = tg[base + lane];

    float z[4];
#pragma unroll
    for (int c = 0; c < 4; c++) {
      const int px = base + 16 * c + o;   // this lane's pixel column
      const int hh = px / Wc;
      const float xr = ((float)(px - hh * Wc) - x0) * 0.0078125f;
      const float yr = ((float)hh - y0) * 0.0078125f;
      f32x4 c1;
#pragma unroll
      for (int r = 0; r < 4; r++) c1[r] = b1r[r] + w16r[r] * xr + w17r[r] * yr;
      f32x4 d1 = __builtin_amdgcn_mfma_f32_16x16x32_bf16(A1.v, B1[c].v, c1, 0, 0, 0);
      // relu + pack: lane holds channels 4g..4g+3 of pixel px
      uint p0 = pkbf(fmaxf(d1[0], 0.0f), fmaxf(d1[1], 0.0f));
      uint p1 = pkbf(fmaxf(d1[2], 0.0f), fmaxf(d1[3], 0.0f));
      // redistribute to B2 frag: lane (g,j) needs channels 8g..8g+7 of pixel j
      uint s16_0 = __shfl_xor(p0, 16), s16_1 = __shfl_xor(p1, 16);
      uint s32_0 = __shfl_xor(p0, 32), s32_1 = __shfl_xor(p1, 32);
      uint s48_0 = __shfl_xor(p0, 48), s48_1 = __shfl_xor(p1, 48);
      const bool odd = (g & 1);
      FR B2;
      B2.u[0] = odd ? s48_0 : p0;
      B2.u[1] = odd ? s48_1 : p1;
      B2.u[2] = odd ? s32_0 : s16_0;
      B2.u[3] = odd ? s32_1 : s16_1;
      f32x4 c2;
#pragma unroll
      for (int r = 0; r < 4; r++) c2[r] = b2r[r];
      f32x4 d2 = __builtin_amdgcn_mfma_f32_16x16x32_bf16(A2.v, B2.v, c2, 0, 0, 0);
      // layer3: partial over this lane's 4 output channels, then reduce over groups
      float zp = fmaxf(d2[0], 0.0f) * w3r[0] + fmaxf(d2[1], 0.0f) * w3r[1] +
                 fmaxf(d2[2], 0.0f) * w3r[2] + fmaxf(d2[3], 0.0f) * w3r[3];
      zp += __shfl_xor(zp, 16);
      zp += __shfl_xor(zp, 32);
      z[c] = zp;  // z for pixel (base+16c+(l&15)), replicated over groups
    }
    // lane l handles pixel base + l  (chain c = l>>4, column j = l&15)
    float zz = (lane & 32) ? ((lane & 16) ? z[3] : z[2]) : ((lane & 16) ? z[1] : z[0]);
    zz += b3;
    float hm = __fdividef(1.0f, 1.0f + __expf(-zz));
    hm = fminf(fmaxf(hm, 1e-4f), 1.0f - 1e-4f);
    const float u = 1.0f - tval;
    const float u2 = u * u;
    acc += __logf(1.0f - hm) * hm * hm * (u2 * u2);
  }

  __shared__ float red[256];
  red[tid] = acc;
  __syncthreads();
  for (int s = 128; s > 0; s >>= 1) {
    if (tid < s) red[tid] += red[tid + s];
    __syncthreads();
  }
  if (tid == 0) ws[blockIdx.x] = red[0];
}

// ---- positive-sample terms: exact fp32, one thread per (b,m) ----
__global__ __launch_bounds__(128) void sch_pos(const float* __restrict__ sf_all,
                                               const float* __restrict__ cw,
                                               const int* __restrict__ pre_ind,
                                               const int* __restrict__ ind,
                                               const float* __restrict__ mask,
                                               float* __restrict__ ws) {
  const int bm = threadIdx.x;
  if (bm >= Bc * Mc) return;
  const int b = bm >> 5;
  const int p = pre_ind[bm];
  const float* wcol = cw + (size_t)b * WTc * HWc + p;
  auto wld = [&](int j) -> float { return wcol[(size_t)j * HWc]; };
  const float* sf = sf_all + (size_t)b * 16 * HWc;
  const int pi = ind[bm];

  float f[18];
#pragma unroll
  for (int c = 0; c < 16; c++) f[c] = sf[(size_t)c * HWc + pi];
  const int hh = pi / Wc;
  const float x0 = (float)(p % Wc);
  const float y0 = (float)p / (float)Wc;
  f[16] = ((float)(pi - hh * Wc) - x0) * 0.0078125f;
  f[17] = ((float)hh - y0) * 0.0078125f;

  float h1[16];
  for (int oo = 0; oo < 16; oo++) {
    float a = wld(288 + oo);
#pragma unroll
    for (int c = 0; c < 18; c++) a = fmaf(wld(oo * 18 + c), f[c], a);
    h1[oo] = fmaxf(a, 0.0f);
  }
  float h2[16];
  for (int oo = 0; oo < 16; oo++) {
    float a = wld(560 + oo);
#pragma unroll
    for (int c = 0; c < 16; c++) a = fmaf(wld(304 + oo * 16 + c), h1[c], a);
    h2[oo] = fmaxf(a, 0.0f);
  }
  float zv = wld(592);
#pragma unroll
  for (int c = 0; c < 16; c++) zv = fmaf(wld(576 + c), h2[c], zv);
  float hm = __fdividef(1.0f, 1.0f + __expf(-zv));
  hm = fminf(fmaxf(hm, 1e-4f), 1.0f - 1e-4f);
  const float om = 1.0f - hm;
  ws[POS_OFF + bm] = __logf(hm) * om * om * mask[bm];
}

// ---- final reduction ----
__global__ __launch_bounds__(256) void sch_final(const float* __restrict__ ws,
                                                 const float* __restrict__ mask,
                                                 float* __restrict__ out) {
  __shared__ float red[256];
  const int t = threadIdx.x;

  float s = 0.0f;
  for (int i = t; i < NEG_BLOCKS; i += 256) s += ws[i];
  red[t] = s; __syncthreads();
  for (int k = 128; k > 0; k >>= 1) { if (t < k) red[t] += red[t + k]; __syncthreads(); }
  const float neg = red[0];
  __syncthreads();

  float pv = (t < Bc * Mc) ? ws[POS_OFF + t] : 0.0f;
  red[t] = pv; __syncthreads();
  for (int k = 128; k > 0; k >>= 1) { if (t < k) red[t] += red[t + k]; __syncthreads(); }
  const float pos = red[0];
  __syncthreads();

  float mv = (t < Bc * Mc) ? mask[t] : 0.0f;
  red[t] = mv; __syncthreads();
  for (int k = 128; k > 0; k >>= 1) { if (t < k) red[t] += red[t + k]; __syncthreads(); }

  if (t == 0) {
    float np = red[0];
    out[0] = (np == 0.0f) ? (-neg) : (-(pos + neg) / fmaxf(np, 1.0f));
  }
}

extern "C" void kernel_launch(void* const* d_in, const int* in_sizes, int n_in,
                              void* d_out, int out_size, void* d_ws, size_t ws_size,
                              hipStream_t stream) {
  const float* sch_feat    = (const float*)d_in[0];
  const float* conv_weight = (const float*)d_in[1];
  const float* mask        = (const float*)d_in[2];
  const int*   pre_ind     = (const int*)d_in[3];
  const float* target      = (const float*)d_in[4];
  const int*   ind         = (const int*)d_in[5];
  float* out = (float*)d_out;
  float* ws  = (float*)d_ws;
  ushort* xbf = (ushort*)((char*)d_ws + XOFF_BYTES);

  xcvt_kernel<<<dim3((HWc + 255) / 256, Bc), dim3(256), 0, stream>>>(sch_feat, xbf);
  sch_neg<<<dim3(NEG_BLOCKS), dim3(256), 0, stream>>>(conv_weight, pre_ind, target, xbf, ws);
  sch_pos<<<dim3(1), dim3(128), 0, stream>>>(sch_feat, conv_weight, pre_ind, ind, mask, ws);
  sch_final<<<dim3(1), dim3(256), 0, stream>>>(ws, mask, out);
}

// Round 3
// 75.451 us; speedup vs baseline: 20.6141x; 3.3937x over previous
//
#include <hip/hip_runtime.h>

typedef unsigned int uint;
typedef unsigned short ushort;

constexpr int Bc = 4, Mc = 32, Hc = 152, Wc = 272;
constexpr int HWc = Hc * Wc;              // 41344
constexpr int WTc = 593;                  // (16+2)*16 + 16 + 16*16 + 16 + 16 + 1
constexpr int NB = 8;                     // blocks per (b,m)
constexpr int NEG_BLOCKS = Bc * Mc * NB;  // 1024
constexpr int ITERS = HWc / 64;           // 646 (exact)
constexpr int WV = NB * 4;                // waves per (b,m)
constexpr int POS_OFF = 1024;             // ws float idx of pos terms
constexpr int WC_OFF = 2048;              // ws float idx of compact weights
constexpr int WC_STRIDE = 600;
constexpr int APK1_OFF = WC_OFF + 128 * WC_STRIDE;  // 78848 (float slots)
constexpr int APK2_OFF = APK1_OFF + 128 * 64 * 4;   // +32768
constexpr size_t XOFF_BYTES = (size_t)(APK2_OFF + 128 * 64 * 4) * 4;  // 577536, 64B-aligned

using f32x4 = __attribute__((ext_vector_type(4))) float;
using bf16x8 = __attribute__((ext_vector_type(8))) short;

__device__ inline uint pkbf(float lo, float hi) {
  uint r;
  asm("v_cvt_pk_bf16_f32 %0, %1, %2" : "=v"(r) : "v"(lo), "v"(hi));
  return r;
}
__device__ inline float bpermf(int byteaddr, float v) {
  return __int_as_float(__builtin_amdgcn_ds_bpermute(byteaddr, __float_as_int(v)));
}
__device__ inline uint bpermu(int byteaddr, uint v) {
  return (uint)__builtin_amdgcn_ds_bpermute(byteaddr, (int)v);
}

union FR { uint u[4]; bf16x8 v; };

// ---- pre-pass A: sch_feat fp32 [b][c][hw] -> bf16 pixel-major [b][px][c] ----
__global__ __launch_bounds__(256) void xcvt_kernel(const float* __restrict__ sf,
                                                   ushort* __restrict__ xb) {
  const int b = blockIdx.y;
  const int px = blockIdx.x * 256 + threadIdx.x;
  if (px < HWc) {
    const float* s = sf + (size_t)b * 16 * HWc + px;
    uint o[8];
#pragma unroll
    for (int q = 0; q < 8; q++) o[q] = pkbf(s[(size_t)(2 * q) * HWc], s[(size_t)(2 * q + 1) * HWc]);
    uint4* dst = (uint4*)(xb + ((size_t)b * HWc + px) * 16);
    dst[0] = make_uint4(o[0], o[1], o[2], o[3]);
    dst[1] = make_uint4(o[4], o[5], o[6], o[7]);
  }
  if (blockIdx.x == 0 && blockIdx.y == 0 && threadIdx.x < 32)
    ((uint*)(xb + (size_t)Bc * HWc * 16))[threadIdx.x] = 0;  // tail pad
}

// ---- pre-pass B: gather 593 weights once per (b,m); pack A-fragments ----
__global__ __launch_bounds__(256) void prep_kernel(const float* __restrict__ cw,
                                                   const int* __restrict__ pre_ind,
                                                   float* __restrict__ ws) {
  const int bm = blockIdx.x, b = bm >> 5, tid = threadIdx.x;
  const int p = pre_ind[bm];
  __shared__ float sw[WTc];
  const float* wcol = cw + (size_t)b * WTc * HWc + p;
  float* wc = ws + WC_OFF + bm * WC_STRIDE;
  for (int j = tid; j < WTc; j += 256) {
    float v = wcol[(size_t)j * HWc];
    sw[j] = v;
    wc[j] = v;
  }
  __syncthreads();
  if (tid < 64) {
    const int g = tid >> 4, o = tid & 15;
    float a1f[8], a2f[8];
#pragma unroll
    for (int e = 0; e < 8; e++) {
      int k = 8 * g + e;
      a1f[e] = (k < 16) ? sw[o * 18 + k] : 0.0f;
      a2f[e] = (k < 16) ? sw[304 + o * 16 + k] : 0.0f;
    }
    uint4 u1, u2;
    u1.x = pkbf(a1f[0], a1f[1]); u1.y = pkbf(a1f[2], a1f[3]);
    u1.z = pkbf(a1f[4], a1f[5]); u1.w = pkbf(a1f[6], a1f[7]);
    u2.x = pkbf(a2f[0], a2f[1]); u2.y = pkbf(a2f[2], a2f[3]);
    u2.z = pkbf(a2f[4], a2f[5]); u2.w = pkbf(a2f[6], a2f[7]);
    ((uint4*)(ws + APK1_OFF))[bm * 64 + tid] = u1;
    ((uint4*)(ws + APK2_OFF))[bm * 64 + tid] = u2;
  }
}

// ---- main negative-loss kernel ----
__global__ __launch_bounds__(256) void sch_neg(const float* __restrict__ target,
                                               const ushort* __restrict__ xbf,
                                               const int* __restrict__ pre_ind,
                                               float* __restrict__ ws) {
  const int tid = threadIdx.x;
  const int lane = tid & 63;
  const int wid = tid >> 6;
  const int bm = blockIdx.x / NB;
  const int nb = blockIdx.x % NB;
  const int b = bm >> 5;
  const int g = lane >> 4;
  const int o = lane & 15;

  const int p = pre_ind[bm];
  const float x0 = (float)(p % Wc);
  const float y0 = (float)p / (float)Wc;  // float division of flat index (per reference)

  FR A1, A2;
  {
    uint4 u1 = ((const uint4*)(ws + APK1_OFF))[bm * 64 + lane];
    uint4 u2 = ((const uint4*)(ws + APK2_OFF))[bm * 64 + lane];
    A1.u[0] = u1.x; A1.u[1] = u1.y; A1.u[2] = u1.z; A1.u[3] = u1.w;
    A2.u[0] = u2.x; A2.u[1] = u2.y; A2.u[2] = u2.z; A2.u[3] = u2.w;
  }
  const float* wc = ws + WC_OFF + bm * WC_STRIDE;
  float b1r[4], w16r[4], w17r[4], b2r[4], w3r[4];
#pragma unroll
  for (int r = 0; r < 4; r++) {
    int row = 4 * g + r;
    b1r[r] = wc[288 + row];
    w16r[r] = wc[row * 18 + 16];
    w17r[r] = wc[row * 18 + 17];
    b2r[r] = wc[560 + row];
    w3r[r] = wc[576 + row];
  }
  const float b3 = wc[592];

  const ushort* xb = xbf + (size_t)b * HWc * 16;
  const float* tg = target + (size_t)bm * HWc;

  // hoisted bpermute byte-addresses
  const int aX16 = (lane ^ 16) << 2;
  const int aX32 = (lane ^ 32) << 2;
  const int aS0 = (o + ((g == 1) ? 32 : 0)) << 2;   // B2 src for u[0],u[1]
  const int aS1 = (o + ((g == 1) ? 48 : 16)) << 2;  // B2 src for u[2],u[3]

  float acc = 0.0f;
  const int gw = nb * 4 + wid;
  for (int it = gw; it < ITERS; it += WV) {
    const int base = it * 64;
    uint4 ld[4];
#pragma unroll
    for (int c = 0; c < 4; c++)
      ld[c] = *(const uint4*)(xb + ((size_t)(base + 16 * c + o)) * 16 + g * 8);
    const float tval = tg[base + lane];

    float zpv[4];
#pragma unroll
    for (int c = 0; c < 4; c++) {
      FR B1;
      B1.u[0] = ld[c].x; B1.u[1] = ld[c].y; B1.u[2] = ld[c].z; B1.u[3] = ld[c].w;
      const int px = base + 16 * c + o;
      const int hh = px / Wc;
      const float xr = ((float)(px - hh * Wc) - x0) * 0.0078125f;
      const float yr = ((float)hh - y0) * 0.0078125f;
      f32x4 c1;
#pragma unroll
      for (int r = 0; r < 4; r++) c1[r] = b1r[r] + w16r[r] * xr + w17r[r] * yr;
      f32x4 d1 = __builtin_amdgcn_mfma_f32_16x16x32_bf16(A1.v, B1.v, c1, 0, 0, 0);
      uint p0 = pkbf(fmaxf(d1[0], 0.0f), fmaxf(d1[1], 0.0f));
      uint p1 = pkbf(fmaxf(d1[2], 0.0f), fmaxf(d1[3], 0.0f));
      FR B2;
      B2.u[0] = bpermu(aS0, p0);
      B2.u[1] = bpermu(aS0, p1);
      B2.u[2] = bpermu(aS1, p0);
      B2.u[3] = bpermu(aS1, p1);
      f32x4 c2;
#pragma unroll
      for (int r = 0; r < 4; r++) c2[r] = b2r[r];
      f32x4 d2 = __builtin_amdgcn_mfma_f32_16x16x32_bf16(A2.v, B2.v, c2, 0, 0, 0);
      zpv[c] = fmaxf(d2[0], 0.0f) * w3r[0] + fmaxf(d2[1], 0.0f) * w3r[1] +
               fmaxf(d2[2], 0.0f) * w3r[2] + fmaxf(d2[3], 0.0f) * w3r[3];
    }
    // packed 2-round transpose-reduce: S = sum_{g'} zp(g', c = g)
    const int b0 = g & 1, b1 = g & 2;
    const float pk_g  = b1 ? (b0 ? zpv[3] : zpv[2]) : (b0 ? zpv[1] : zpv[0]);  // zpv[g]
    const float pk_g1 = b1 ? (b0 ? zpv[2] : zpv[3]) : (b0 ? zpv[0] : zpv[1]);  // zpv[g^1]
    const float pk_g2 = b1 ? (b0 ? zpv[1] : zpv[0]) : (b0 ? zpv[3] : zpv[2]);  // zpv[g^2]
    const float pk_g3 = b1 ? (b0 ? zpv[0] : zpv[1]) : (b0 ? zpv[2] : zpv[3]);  // zpv[g^3]
    const float tA = pk_g + bpermf(aX16, pk_g1);
    const float tB = pk_g2 + bpermf(aX16, pk_g3);
    const float S = tA + bpermf(aX32, tB);

    const float zz = S + b3;
    float hm = __fdividef(1.0f, 1.0f + __expf(-zz));
    hm = fminf(fmaxf(hm, 1e-4f), 1.0f - 1e-4f);
    const float u = 1.0f - tval;
    const float u2 = u * u;
    acc += __logf(1.0f - hm) * hm * hm * (u2 * u2);
  }

  __shared__ float red[256];
  red[tid] = acc;
  __syncthreads();
  for (int s = 128; s > 0; s >>= 1) {
    if (tid < s) red[tid] += red[tid + s];
    __syncthreads();
  }
  if (tid == 0) ws[blockIdx.x] = red[0];
}

// ---- positive-sample terms: exact fp32 from compact weights ----
__global__ __launch_bounds__(128) void sch_pos(const float* __restrict__ sf_all,
                                               const int* __restrict__ pre_ind,
                                               const int* __restrict__ ind,
                                               const float* __restrict__ mask,
                                               float* __restrict__ ws) {
  const int bm = threadIdx.x;
  if (bm >= Bc * Mc) return;
  const int b = bm >> 5;
  const int p = pre_ind[bm];
  const float* wc = ws + WC_OFF + bm * WC_STRIDE;
  const float* sf = sf_all + (size_t)b * 16 * HWc;
  const int pi = ind[bm];

  float f[18];
#pragma unroll
  for (int c = 0; c < 16; c++) f[c] = sf[(size_t)c * HWc + pi];
  const int hh = pi / Wc;
  const float x0 = (float)(p % Wc);
  const float y0 = (float)p / (float)Wc;
  f[16] = ((float)(pi - hh * Wc) - x0) * 0.0078125f;
  f[17] = ((float)hh - y0) * 0.0078125f;

  float h1[16];
  for (int oo = 0; oo < 16; oo++) {
    float a = wc[288 + oo];
#pragma unroll
    for (int c = 0; c < 18; c++) a = fmaf(wc[oo * 18 + c], f[c], a);
    h1[oo] = fmaxf(a, 0.0f);
  }
  float h2[16];
  for (int oo = 0; oo < 16; oo++) {
    float a = wc[560 + oo];
#pragma unroll
    for (int c = 0; c < 16; c++) a = fmaf(wc[304 + oo * 16 + c], h1[c], a);
    h2[oo] = fmaxf(a, 0.0f);
  }
  float zv = wc[592];
#pragma unroll
  for (int c = 0; c < 16; c++) zv = fmaf(wc[576 + c], h2[c], zv);
  float hm = __fdividef(1.0f, 1.0f + __expf(-zv));
  hm = fminf(fmaxf(hm, 1e-4f), 1.0f - 1e-4f);
  const float om = 1.0f - hm;
  ws[POS_OFF + bm] = __logf(hm) * om * om * mask[bm];
}

// ---- final reduction ----
__global__ __launch_bounds__(256) void sch_final(const float* __restrict__ ws,
                                                 const float* __restrict__ mask,
                                                 float* __restrict__ out) {
  __shared__ float red[256];
  const int t = threadIdx.x;

  float s = 0.0f;
  for (int i = t; i < NEG_BLOCKS; i += 256) s += ws[i];
  red[t] = s; __syncthreads();
  for (int k = 128; k > 0; k >>= 1) { if (t < k) red[t] += red[t + k]; __syncthreads(); }
  const float neg = red[0];
  __syncthreads();

  float pv = (t < Bc * Mc) ? ws[POS_OFF + t] : 0.0f;
  red[t] = pv; __syncthreads();
  for (int k = 128; k > 0; k >>= 1) { if (t < k) red[t] += red[t + k]; __syncthreads(); }
  const float pos = red[0];
  __syncthreads();

  float mv = (t < Bc * Mc) ? mask[t] : 0.0f;
  red[t] = mv; __syncthreads();
  for (int k = 128; k > 0; k >>= 1) { if (t < k) red[t] += red[t + k]; __syncthreads(); }

  if (t == 0) {
    float np = red[0];
    out[0] = (np == 0.0f) ? (-neg) : (-(pos + neg) / fmaxf(np, 1.0f));
  }
}

extern "C" void kernel_launch(void* const* d_in, const int* in_sizes, int n_in,
                              void* d_out, int out_size, void* d_ws, size_t ws_size,
                              hipStream_t stream) {
  const float* sch_feat    = (const float*)d_in[0];
  const float* conv_weight = (const float*)d_in[1];
  const float* mask        = (const float*)d_in[2];
  const int*   pre_ind     = (const int*)d_in[3];
  const float* target      = (const float*)d_in[4];
  const int*   ind         = (const int*)d_in[5];
  float* out = (float*)d_out;
  float* ws  = (float*)d_ws;
  ushort* xbf = (ushort*)((char*)d_ws + XOFF_BYTES);

  xcvt_kernel<<<dim3((HWc + 255) / 256, Bc), dim3(256), 0, stream>>>(sch_feat, xbf);
  prep_kernel<<<dim3(Bc * Mc), dim3(256), 0, stream>>>(conv_weight, pre_ind, ws);
  sch_neg<<<dim3(NEG_BLOCKS), dim3(256), 0, stream>>>(target, xbf, pre_ind, ws);
  sch_pos<<<dim3(1), dim3(128), 0, stream>>>(sch_feat, pre_ind, ind, mask, ws);
  sch_final<<<dim3(1), dim3(256), 0, stream>>>(ws, mask, out);
}

// Round 4
// 49.158 us; speedup vs baseline: 31.6400x; 1.5349x over previous
//
#include <hip/hip_runtime.h>

typedef unsigned int uint;
typedef unsigned short ushort;

constexpr int Bc = 4, Mc = 32, Hc = 152, Wc = 272;
constexpr int HWc = Hc * Wc;              // 41344
constexpr int WTc = 593;                  // (16+2)*16 + 16 + 16*16 + 16 + 16 + 1
constexpr int NB = 8;                     // blocks per (b,m)
constexpr int NEG_BLOCKS = Bc * Mc * NB;  // 1024
constexpr int ITERS = HWc / 64;           // 646 (exact)
constexpr int POS_OFF = 1024;             // ws float idx of pos terms
constexpr int WC_OFF = 2048;              // ws float idx of compact weights
constexpr int WC_STRIDE = 600;
constexpr int APK1_OFF = WC_OFF + 128 * WC_STRIDE;  // 78848
constexpr int APK2_OFF = APK1_OFF + 128 * 64 * 4;   // 111616
constexpr size_t XOFF_BYTES = (size_t)(APK2_OFF + 128 * 64 * 4) * 4;  // 577536
constexpr int CH = 24;                    // stored ushort channels/pixel (48B)
constexpr int XCVT_BLOCKS = 162 * Bc;     // 648

using f32x4 = __attribute__((ext_vector_type(4))) float;
using bf16x8 = __attribute__((ext_vector_type(8))) short;

__device__ inline uint pkbf(float lo, float hi) {
  uint r;
  asm("v_cvt_pk_bf16_f32 %0, %1, %2" : "=v"(r) : "v"(lo), "v"(hi));
  return r;
}
__device__ inline float bpermf(int byteaddr, float v) {
  return __int_as_float(__builtin_amdgcn_ds_bpermute(byteaddr, __float_as_int(v)));
}
__device__ inline uint bpermu(int byteaddr, uint v) {
  return (uint)__builtin_amdgcn_ds_bpermute(byteaddr, (int)v);
}

union FR { uint u[4]; bf16x8 v; };

// ---- fused pre-pass: xcvt blocks + prep/pos blocks ----
__global__ __launch_bounds__(256) void fused_pre(const float* __restrict__ sf_all,
                                                 const float* __restrict__ cw,
                                                 const int* __restrict__ pre_ind,
                                                 const int* __restrict__ ind,
                                                 const float* __restrict__ mask,
                                                 ushort* __restrict__ xb,
                                                 float* __restrict__ ws) {
  __shared__ float sw[WTc];
  const int blk = blockIdx.x, tid = threadIdx.x;

  if (blk < XCVT_BLOCKS) {
    // sch_feat fp32 [b][c][hw] -> bf16 pixel-major, 24 ch: 16 feat + x/128 + y/128 + pad
    const int b = blk / 162, bx = blk - b * 162;
    const int px = bx * 256 + tid;
    if (px < HWc) {
      const float* s = sf_all + (size_t)b * 16 * HWc + px;
      uint q[8];
#pragma unroll
      for (int i = 0; i < 8; i++) q[i] = pkbf(s[(size_t)(2 * i) * HWc], s[(size_t)(2 * i + 1) * HWc]);
      const int hh = px / Wc, xx = px - hh * Wc;
      const uint q8 = pkbf((float)xx * 0.0078125f, (float)hh * 0.0078125f);
      uint4* dst = (uint4*)(xb + ((size_t)b * HWc + px) * CH);
      dst[0] = make_uint4(q[0], q[1], q[2], q[3]);
      dst[1] = make_uint4(q[4], q[5], q[6], q[7]);
      dst[2] = make_uint4(q8, 0u, 0u, 0u);
    }
    if (blk == 0 && tid < 32) ((uint*)(xb + (size_t)Bc * HWc * CH))[tid] = 0;  // 128B tail pad
    return;
  }

  // prep: gather 593 weights once per (b,m); pack A-fragments; pos term
  const int bm = blk - XCVT_BLOCKS, b = bm >> 5;
  const int p = pre_ind[bm];
  const float* wcol = cw + (size_t)b * WTc * HWc + p;
  float* wc = ws + WC_OFF + bm * WC_STRIDE;
  for (int j = tid; j < WTc; j += 256) {
    float v = wcol[(size_t)j * HWc];
    sw[j] = v;
    wc[j] = v;
  }
  __syncthreads();

  if (tid < 64) {
    const int g = tid >> 4, o = tid & 15;
    float a1f[8], a2f[8];
#pragma unroll
    for (int e = 0; e < 8; e++) {
      int k = 8 * g + e;
      a1f[e] = (k < 18) ? sw[o * 18 + k] : 0.0f;   // k=16,17 -> coord weights
      a2f[e] = (k < 16) ? sw[304 + o * 16 + k] : 0.0f;
    }
    uint4 u1, u2;
    u1.x = pkbf(a1f[0], a1f[1]); u1.y = pkbf(a1f[2], a1f[3]);
    u1.z = pkbf(a1f[4], a1f[5]); u1.w = pkbf(a1f[6], a1f[7]);
    u2.x = pkbf(a2f[0], a2f[1]); u2.y = pkbf(a2f[2], a2f[3]);
    u2.z = pkbf(a2f[4], a2f[5]); u2.w = pkbf(a2f[6], a2f[7]);
    ((uint4*)(ws + APK1_OFF))[bm * 64 + tid] = u1;
    ((uint4*)(ws + APK2_OFF))[bm * 64 + tid] = u2;
  } else if (tid == 64) {
    // positive-sample term, exact fp32
    const float* sf = sf_all + (size_t)b * 16 * HWc;
    const int pi = ind[bm];
    float f[18];
#pragma unroll
    for (int c = 0; c < 16; c++) f[c] = sf[(size_t)c * HWc + pi];
    const int hh = pi / Wc;
    const float x0 = (float)(p % Wc);
    const float y0 = (float)p / (float)Wc;
    f[16] = ((float)(pi - hh * Wc) - x0) * 0.0078125f;
    f[17] = ((float)hh - y0) * 0.0078125f;
    float h1[16];
    for (int oo = 0; oo < 16; oo++) {
      float a = sw[288 + oo];
#pragma unroll
      for (int c = 0; c < 18; c++) a = fmaf(sw[oo * 18 + c], f[c], a);
      h1[oo] = fmaxf(a, 0.0f);
    }
    float h2[16];
    for (int oo = 0; oo < 16; oo++) {
      float a = sw[560 + oo];
#pragma unroll
      for (int c = 0; c < 16; c++) a = fmaf(sw[304 + oo * 16 + c], h1[c], a);
      h2[oo] = fmaxf(a, 0.0f);
    }
    float zv = sw[592];
#pragma unroll
    for (int c = 0; c < 16; c++) zv = fmaf(sw[576 + c], h2[c], zv);
    float hm = __fdividef(1.0f, 1.0f + __expf(-zv));
    hm = fminf(fmaxf(hm, 1e-4f), 1.0f - 1e-4f);
    const float om = 1.0f - hm;
    ws[POS_OFF + bm] = __logf(hm) * om * om * mask[bm];
  }
}

// ---- main negative-loss kernel ----
__global__ __launch_bounds__(256, 4) void sch_neg(const float* __restrict__ target,
                                                  const ushort* __restrict__ xbf,
                                                  const int* __restrict__ pre_ind,
                                                  float* __restrict__ ws) {
  const int tid = threadIdx.x;
  const int lane = tid & 63;
  const int wid = tid >> 6;
  // XCD-aware swizzle: batch b pinned to XCD pair {2b, 2b+1} (round-robin heuristic)
  const int xcd = blockIdx.x & 7;
  const int slot = blockIdx.x >> 3;
  const int b = xcd >> 1;
  const int m = slot & 31;
  const int nb = ((slot >> 5) << 1) | (xcd & 1);
  const int bm = (b << 5) | m;
  const int g = lane >> 4;
  const int o = lane & 15;

  const int p = pre_ind[bm];
  const float x0 = (float)(p % Wc);
  const float y0 = (float)p / (float)Wc;  // float division of flat index (per reference)

  FR A1, A2;
  {
    uint4 u1 = ((const uint4*)(ws + APK1_OFF))[bm * 64 + lane];
    uint4 u2 = ((const uint4*)(ws + APK2_OFF))[bm * 64 + lane];
    A1.u[0] = u1.x; A1.u[1] = u1.y; A1.u[2] = u1.z; A1.u[3] = u1.w;
    A2.u[0] = u2.x; A2.u[1] = u2.y; A2.u[2] = u2.z; A2.u[3] = u2.w;
  }
  const float* wc = ws + WC_OFF + bm * WC_STRIDE;
  f32x4 c1v, c2v;
  float w3r[4];
#pragma unroll
  for (int r = 0; r < 4; r++) {
    int row = 4 * g + r;
    // fold coord offsets into layer-1 bias: w16*(x/128) comes via MFMA channel 16
    c1v[r] = wc[288 + row] - (wc[row * 18 + 16] * x0 + wc[row * 18 + 17] * y0) * 0.0078125f;
    c2v[r] = wc[560 + row];
    w3r[r] = wc[576 + row];
  }
  const float b3 = wc[592];

  const ushort* xb = xbf + (size_t)b * HWc * CH;
  const float* tg = target + (size_t)bm * HWc;

  const int aX16 = (lane ^ 16) << 2;
  const int aX32 = (lane ^ 32) << 2;
  const int aS0 = (o + ((g == 1) ? 32 : 0)) << 2;
  const int aS1 = (o + ((g == 1) ? 48 : 16)) << 2;

  float acc = 0.0f;
  const int gw = nb * 4 + wid;
  for (int it = gw; it < ITERS; it += 32) {
    const int base = it * 64;
    uint4 ld[4];
#pragma unroll
    for (int c = 0; c < 4; c++)
      ld[c] = *(const uint4*)(xb + (size_t)(base + 16 * c + o) * CH + g * 8);
    const float tval = tg[base + lane];

    float zpv[4];
#pragma unroll
    for (int half = 0; half < 2; half++) {
      FR B1a, B1b;
      B1a.u[0] = ld[2 * half].x; B1a.u[1] = ld[2 * half].y;
      B1a.u[2] = ld[2 * half].z; B1a.u[3] = ld[2 * half].w;
      B1b.u[0] = ld[2 * half + 1].x; B1b.u[1] = ld[2 * half + 1].y;
      B1b.u[2] = ld[2 * half + 1].z; B1b.u[3] = ld[2 * half + 1].w;
      f32x4 d1a = __builtin_amdgcn_mfma_f32_16x16x32_bf16(A1.v, B1a.v, c1v, 0, 0, 0);
      f32x4 d1b = __builtin_amdgcn_mfma_f32_16x16x32_bf16(A1.v, B1b.v, c1v, 0, 0, 0);
      uint pa0 = pkbf(fmaxf(d1a[0], 0.0f), fmaxf(d1a[1], 0.0f));
      uint pa1 = pkbf(fmaxf(d1a[2], 0.0f), fmaxf(d1a[3], 0.0f));
      uint pb0 = pkbf(fmaxf(d1b[0], 0.0f), fmaxf(d1b[1], 0.0f));
      uint pb1 = pkbf(fmaxf(d1b[2], 0.0f), fmaxf(d1b[3], 0.0f));
      FR B2a, B2b;
      B2a.u[0] = bpermu(aS0, pa0); B2a.u[1] = bpermu(aS0, pa1);
      B2a.u[2] = bpermu(aS1, pa0); B2a.u[3] = bpermu(aS1, pa1);
      B2b.u[0] = bpermu(aS0, pb0); B2b.u[1] = bpermu(aS0, pb1);
      B2b.u[2] = bpermu(aS1, pb0); B2b.u[3] = bpermu(aS1, pb1);
      f32x4 d2a = __builtin_amdgcn_mfma_f32_16x16x32_bf16(A2.v, B2a.v, c2v, 0, 0, 0);
      f32x4 d2b = __builtin_amdgcn_mfma_f32_16x16x32_bf16(A2.v, B2b.v, c2v, 0, 0, 0);
      zpv[2 * half] = fmaxf(d2a[0], 0.0f) * w3r[0] + fmaxf(d2a[1], 0.0f) * w3r[1] +
                      fmaxf(d2a[2], 0.0f) * w3r[2] + fmaxf(d2a[3], 0.0f) * w3r[3];
      zpv[2 * half + 1] = fmaxf(d2b[0], 0.0f) * w3r[0] + fmaxf(d2b[1], 0.0f) * w3r[1] +
                          fmaxf(d2b[2], 0.0f) * w3r[2] + fmaxf(d2b[3], 0.0f) * w3r[3];
    }
    // packed 2-round transpose-reduce: S(pixel base+lane) = sum_g zpv
    const int b0 = g & 1, b1 = g & 2;
    const float pk_g  = b1 ? (b0 ? zpv[3] : zpv[2]) : (b0 ? zpv[1] : zpv[0]);
    const float pk_g1 = b1 ? (b0 ? zpv[2] : zpv[3]) : (b0 ? zpv[0] : zpv[1]);
    const float pk_g2 = b1 ? (b0 ? zpv[1] : zpv[0]) : (b0 ? zpv[3] : zpv[2]);
    const float pk_g3 = b1 ? (b0 ? zpv[0] : zpv[1]) : (b0 ? zpv[2] : zpv[3]);
    const float tA = pk_g + bpermf(aX16, pk_g1);
    const float tB = pk_g2 + bpermf(aX16, pk_g3);
    const float S = tA + bpermf(aX32, tB);

    const float zz = S + b3;
    float hm = __fdividef(1.0f, 1.0f + __expf(-zz));
    hm = fminf(fmaxf(hm, 1e-4f), 1.0f - 1e-4f);
    const float u = 1.0f - tval;
    const float u2 = u * u;
    acc += __logf(1.0f - hm) * hm * hm * (u2 * u2);
  }

  __shared__ float red[256];
  red[tid] = acc;
  __syncthreads();
  for (int s = 128; s > 0; s >>= 1) {
    if (tid < s) red[tid] += red[tid + s];
    __syncthreads();
  }
  if (tid == 0) ws[blockIdx.x] = red[0];
}

// ---- final reduction ----
__global__ __launch_bounds__(256) void sch_final(const float* __restrict__ ws,
                                                 const float* __restrict__ mask,
                                                 float* __restrict__ out) {
  __shared__ float red[256];
  const int t = threadIdx.x;

  float s = 0.0f;
  for (int i = t; i < NEG_BLOCKS; i += 256) s += ws[i];
  red[t] = s; __syncthreads();
  for (int k = 128; k > 0; k >>= 1) { if (t < k) red[t] += red[t + k]; __syncthreads(); }
  const float neg = red[0];
  __syncthreads();

  float pv = (t < Bc * Mc) ? ws[POS_OFF + t] : 0.0f;
  red[t] = pv; __syncthreads();
  for (int k = 128; k > 0; k >>= 1) { if (t < k) red[t] += red[t + k]; __syncthreads(); }
  const float pos = red[0];
  __syncthreads();

  float mv = (t < Bc * Mc) ? mask[t] : 0.0f;
  red[t] = mv; __syncthreads();
  for (int k = 128; k > 0; k >>= 1) { if (t < k) red[t] += red[t + k]; __syncthreads(); }

  if (t == 0) {
    float np = red[0];
    out[0] = (np == 0.0f) ? (-neg) : (-(pos + neg) / fmaxf(np, 1.0f));
  }
}

extern "C" void kernel_launch(void* const* d_in, const int* in_sizes, int n_in,
                              void* d_out, int out_size, void* d_ws, size_t ws_size,
                              hipStream_t stream) {
  const float* sch_feat    = (const float*)d_in[0];
  const float* conv_weight = (const float*)d_in[1];
  const float* mask        = (const float*)d_in[2];
  const int*   pre_ind     = (const int*)d_in[3];
  const float* target      = (const float*)d_in[4];
  const int*   ind         = (const int*)d_in[5];
  float* out = (float*)d_out;
  float* ws  = (float*)d_ws;
  ushort* xbf = (ushort*)((char*)d_ws + XOFF_BYTES);

  fused_pre<<<dim3(XCVT_BLOCKS + Bc * Mc), dim3(256), 0, stream>>>(
      sch_feat, conv_weight, pre_ind, ind, mask, xbf, ws);
  sch_neg<<<dim3(NEG_BLOCKS), dim3(256), 0, stream>>>(target, xbf, pre_ind, ws);
  sch_final<<<dim3(1), dim3(256), 0, stream>>>(ws, mask, out);
}